// Round 2
// baseline (228.874 us; speedup 1.0000x reference)
//
#include <hip/hip_runtime.h>

#define D 64
#define EPSV 1e-9f

// --- Kernel 1: CSR row offsets from sorted edge_dst via per-node lower_bound ---
__global__ void build_offsets(const int* __restrict__ edge_dst,
                              int* __restrict__ row_off,
                              int n_nodes, int n_edges) {
    int n = blockIdx.x * blockDim.x + threadIdx.x;
    if (n > n_nodes) return;
    int lo = 0, hi = n_edges;
    while (lo < hi) {
        int mid = (lo + hi) >> 1;
        if (edge_dst[mid] < n) lo = mid + 1; else hi = mid;
    }
    row_off[n] = lo;  // first edge with dst >= n
}

// --- Kernel 2: transpose+interleave W0,W1 -> WI[k][d][2] so the layer kernel
// reads one coalesced 8B/lane load per k. WI[(k*64+d)*2+0]=W0[d][k], +1=W1[d][k].
__global__ void make_wi(const float* __restrict__ W0, const float* __restrict__ W1,
                        float* __restrict__ WI) {
    int idx = blockIdx.x * blockDim.x + threadIdx.x;
    if (idx >= D * D) return;
    int d = idx & 63, k = idx >> 6;
    WI[(k * D + d) * 2 + 0] = W0[d * D + k];
    WI[(k * D + d) * 2 + 1] = W1[d * D + k];
}

// --- Kernel 3: one GNN layer. One wave per node.
// Lane geometry for the edge loop: slot = lane>>4 (4 edge slots),
// fo = (lane&15)*4 (16B feature chunk). One dwordx4 gather covers 4 edges;
// 4 unrolled slots -> 16 edges & 4 gathers in flight per iteration.
__global__ __launch_bounds__(256) void layer_kernel(
    const float* __restrict__ feats_in,
    const int*   __restrict__ row_off,
    const int*   __restrict__ edge_src,
    const float* __restrict__ edge_w,
    const float* __restrict__ WI,   // [k][d][2]
    const float* __restrict__ b0,
    const float* __restrict__ b1,
    float* __restrict__ feats_out,
    int n_nodes)
{
    __shared__ float lds_fm[4][D][2];   // [wave][k][{self,msg}]

    const int lane = threadIdx.x & 63;
    const int wib  = threadIdx.x >> 6;
    int node = blockIdx.x * 4 + wib;
    if (node >= n_nodes) node = n_nodes - 1;     // dup work writes identical data
    node = __builtin_amdgcn_readfirstlane(node); // wave-uniform -> scalar loads

    const int s = row_off[node];
    const int e = row_off[node + 1];

    const int slot = lane >> 4;        // 0..3
    const int fo   = (lane & 15) * 4;  // feature float offset (16B aligned)

    float4 acc[4];
    #pragma unroll
    for (int j = 0; j < 4; ++j) acc[j] = make_float4(0.f, 0.f, 0.f, 0.f);
    float wsum = 0.0f;

    for (int base = s; base < e; base += 16) {
        #pragma unroll
        for (int j = 0; j < 4; ++j) {
            const int  ej = base + slot + (j << 2);
            const bool v  = ej < e;
            const float wj = v ? edge_w[ej] : 0.0f;
            const int   sj = edge_src[v ? ej : (e - 1)];
            const float4 f = *(const float4*)(feats_in + sj * D + fo);
            acc[j].x = fmaf(wj, f.x, acc[j].x);
            acc[j].y = fmaf(wj, f.y, acc[j].y);
            acc[j].z = fmaf(wj, f.z, acc[j].z);
            acc[j].w = fmaf(wj, f.w, acc[j].w);
            wsum += wj;
        }
    }

    float4 a;
    a.x = (acc[0].x + acc[1].x) + (acc[2].x + acc[3].x);
    a.y = (acc[0].y + acc[1].y) + (acc[2].y + acc[3].y);
    a.z = (acc[0].z + acc[1].z) + (acc[2].z + acc[3].z);
    a.w = (acc[0].w + acc[1].w) + (acc[2].w + acc[3].w);

    // butterfly over slot bits (lane bits 4,5): every lane ends with totals
    #pragma unroll
    for (int off = 16; off <= 32; off <<= 1) {
        a.x  += __shfl_xor(a.x,  off);
        a.y  += __shfl_xor(a.y,  off);
        a.z  += __shfl_xor(a.z,  off);
        a.w  += __shfl_xor(a.w,  off);
        wsum += __shfl_xor(wsum, off);
    }

    const float inv = 1.0f / (wsum + EPSV);
    if (lane < 16) {                 // slot-0 lanes publish msg[fo..fo+3]
        lds_fm[wib][fo + 0][1] = a.x * inv;
        lds_fm[wib][fo + 1][1] = a.y * inv;
        lds_fm[wib][fo + 2][1] = a.z * inv;
        lds_fm[wib][fo + 3][1] = a.w * inv;
    }
    lds_fm[wib][lane][0] = feats_in[node * D + lane];
    // no __syncthreads: LDS slice is per-wave; lgkmcnt orders intra-wave dep.

    float o = b0[lane] + b1[lane];
    #pragma unroll
    for (int k = 0; k < D; ++k) {
        const float2 xm = *(const float2*)&lds_fm[wib][k][0];
        const float2 wv = *(const float2*)(WI + (k * D + lane) * 2);
        o = fmaf(xm.x, wv.x, o);
        o = fmaf(xm.y, wv.y, o);
    }
    feats_out[node * D + lane] = fmaxf(o, 0.0f);
}

extern "C" void kernel_launch(void* const* d_in, const int* in_sizes, int n_in,
                              void* d_out, int out_size, void* d_ws, size_t ws_size,
                              hipStream_t stream) {
    const float* node_feats = (const float*)d_in[0];
    const int*   edge_src   = (const int*)  d_in[1];
    const int*   edge_dst   = (const int*)  d_in[2];
    const float* edge_w     = (const float*)d_in[3];
    const float* W0         = (const float*)d_in[4];
    const float* b0         = (const float*)d_in[5];
    const float* W1         = (const float*)d_in[6];
    const float* b1         = (const float*)d_in[7];
    float* out = (float*)d_out;

    const int n_nodes = in_sizes[0] / D;   // 50000
    const int n_edges = in_sizes[1];       // 800000

    // workspace layout
    char* ws = (char*)d_ws;
    int*   row_off   = (int*)ws;                 // (n_nodes+1) ints
    float* WI        = (float*)(ws + 204800);    // 32768 B
    float* feats_mid = (float*)(ws + 237568);    // n_nodes*D*4 = 12.8 MB

    build_offsets<<<(n_nodes + 1 + 255) / 256, 256, 0, stream>>>(edge_dst, row_off, n_nodes, n_edges);
    make_wi<<<(D * D + 255) / 256, 256, 0, stream>>>(W0, W1, WI);

    const int grid = (n_nodes + 3) / 4;
    layer_kernel<<<grid, 256, 0, stream>>>(node_feats, row_off, edge_src, edge_w,
                                           WI, b0, b1, feats_mid, n_nodes);
    layer_kernel<<<grid, 256, 0, stream>>>(feats_mid, row_off, edge_src, edge_w,
                                           WI, b0, b1, out, n_nodes);
}